// Round 12
// baseline (258.730 us; speedup 1.0000x reference)
//
#include <hip/hip_runtime.h>
#include <math.h>

#define NNODES 32768
#define NGRAPH 32
#define NPERG  1024
#define KSEL   32
#define FC1_KS 64   // split-K chunks for fc1 (kc = 4096/64 = 64)

__device__ inline float wave_reduce_sum(float v) {
  #pragma unroll
  for (int off = 32; off > 0; off >>= 1) v += __shfl_xor(v, off, 64);
  return v;
}
__device__ inline float wave_reduce_max(float v) {
  #pragma unroll
  for (int off = 32; off > 0; off >>= 1) v = fmaxf(v, __shfl_xor(v, off, 64));
  return v;
}

// ---------------- CSR build ----------------
__global__ void csr_count(const int* __restrict__ dst, int* __restrict__ counts, int E_) {
  int e = blockIdx.x * 256 + threadIdx.x;
  if (e < E_) atomicAdd(&counts[dst[e]], 1);
}

__global__ __launch_bounds__(1024) void csr_scan(const int* __restrict__ counts,
                                                 int* __restrict__ rowptr,
                                                 int* __restrict__ cursor) {
  __shared__ int partial[1024];
  const int tid = threadIdx.x;
  const int base = tid * 32;
  int c[32];
  int s = 0;
  #pragma unroll
  for (int i = 0; i < 32; ++i) { c[i] = counts[base + i]; s += c[i]; }
  partial[tid] = s;
  __syncthreads();
  for (int off = 1; off < 1024; off <<= 1) {
    int t = (tid >= off) ? partial[tid - off] : 0;
    __syncthreads();
    partial[tid] += t;
    __syncthreads();
  }
  int run = partial[tid] - s;  // exclusive prefix
  #pragma unroll
  for (int i = 0; i < 32; ++i) {
    rowptr[base + i] = run;
    cursor[base + i] = run;
    run += c[i];
  }
  if (tid == 1023) rowptr[NNODES] = run;
}

__global__ void csr_fill(const int* __restrict__ src, const int* __restrict__ dst,
                         int* __restrict__ cursor, int* __restrict__ csrsrc, int E_) {
  int e = blockIdx.x * 256 + threadIdx.x;
  if (e < E_) {
    int p = atomicAdd(&cursor[dst[e]], 1);
    csrsrc[p] = src[e];
  }
}

// ---------------- Layer-1 GEMM + fused attention terms (proven, unchanged) ----------------
template <int K, int C, int H>
__global__ __launch_bounds__(256) void gemm_fused(
    const float* __restrict__ X, const float* __restrict__ W,
    const float* __restrict__ al, const float* __restrict__ ar,
    float* __restrict__ F, float* __restrict__ el, float* __restrict__ er) {
  __shared__ float Xs[16][68];
  __shared__ float Ws[16][64];
  __shared__ float redl[64][16];
  __shared__ float redr[64][16];
  const int tid = threadIdx.x;
  const int tx = tid & 15, ty = tid >> 4;
  const int bx = blockIdx.x;
  const int xcd = bx & 7, pos = bx >> 3;
  const int gph = xcd + (pos >> 4) * 8;
  const int row0 = (gph * 16 + (pos & 15)) * 64;
  const int col0 = blockIdx.y * 64;

  float acc[4][4];
  #pragma unroll
  for (int i = 0; i < 4; ++i)
    #pragma unroll
    for (int j = 0; j < 4; ++j) acc[i][j] = 0.f;

  const int rld = tid >> 2;
  const int kq = (tid & 3) * 4;
  const int kw = tid >> 4;
  const int cw = (tid & 15) * 4;

  for (int kt = 0; kt < K; kt += 16) {
    float4 xv = *(const float4*)&X[(size_t)(row0 + rld) * K + kt + kq];
    Xs[kq + 0][rld] = xv.x; Xs[kq + 1][rld] = xv.y;
    Xs[kq + 2][rld] = xv.z; Xs[kq + 3][rld] = xv.w;
    *(float4*)&Ws[kw][cw] = *(const float4*)&W[(size_t)(kt + kw) * C + col0 + cw];
    __syncthreads();
    #pragma unroll
    for (int k = 0; k < 16; ++k) {
      float xr[4], wr[4];
      #pragma unroll
      for (int i = 0; i < 4; ++i) xr[i] = Xs[k][ty * 4 + i];
      #pragma unroll
      for (int j = 0; j < 4; ++j) wr[j] = Ws[k][tx * 4 + j];
      #pragma unroll
      for (int i = 0; i < 4; ++i)
        #pragma unroll
        for (int j = 0; j < 4; ++j) acc[i][j] = fmaf(xr[i], wr[j], acc[i][j]);
    }
    __syncthreads();
  }

  float av[4], rv[4];
  #pragma unroll
  for (int j = 0; j < 4; ++j) { av[j] = al[col0 + tx * 4 + j]; rv[j] = ar[col0 + tx * 4 + j]; }
  #pragma unroll
  for (int i = 0; i < 4; ++i) {
    float4 o = make_float4(acc[i][0], acc[i][1], acc[i][2], acc[i][3]);
    *(float4*)&F[(size_t)(row0 + ty * 4 + i) * C + col0 + tx * 4] = o;
    float pl = acc[i][0] * av[0] + acc[i][1] * av[1] + acc[i][2] * av[2] + acc[i][3] * av[3];
    float pr = acc[i][0] * rv[0] + acc[i][1] * rv[1] + acc[i][2] * rv[2] + acc[i][3] * rv[3];
    redl[ty * 4 + i][tx] = pl;
    redr[ty * 4 + i][tx] = pr;
  }
  __syncthreads();
  if (tid < 64) {
    float s = 0.f, t = 0.f;
    #pragma unroll
    for (int x = 0; x < 16; ++x) { s += redl[tid][x]; t += redr[tid][x]; }
    el[(row0 + tid) * H + blockIdx.y] = s;
    er[(row0 + tid) * H + blockIdx.y] = t;
  }
}

// ---------------- Layer-2 GEMM v2: normalize-on-load, conflict-free tiling ----------------
// Thread owns cols {tx*4..+3} (head 0) and {64+tx*4..+3} (head 1): all LDS ops are
// 16B-stride float4 (2-way max, free). el/er reduced via 16-lane shfl tree (no LDS).
__global__ __launch_bounds__(256) void gemm2_fused(
    const float* __restrict__ X, const float* __restrict__ sc,
    const float* __restrict__ sh, const float* __restrict__ W,
    const float* __restrict__ al, const float* __restrict__ ar,
    float* __restrict__ F, float* __restrict__ el, float* __restrict__ er) {
  __shared__ float Xs[16][68];
  __shared__ float Ws[16][128];
  const int tid = threadIdx.x;
  const int tx = tid & 15, ty = tid >> 4;
  const int bx = blockIdx.x;
  const int xcd = bx & 7, pos = bx >> 3;
  const int gph = xcd + (pos >> 4) * 8;
  const int row0 = (gph * 16 + (pos & 15)) * 64;
  const int b = gph;

  float acc[4][8];
  #pragma unroll
  for (int i = 0; i < 4; ++i)
    #pragma unroll
    for (int j = 0; j < 8; ++j) acc[i][j] = 0.f;

  const int rld = tid >> 2;
  const int kq = (tid & 3) * 4;

  for (int kt = 0; kt < 256; kt += 16) {
    float4 xv = *(const float4*)&X[(size_t)(row0 + rld) * 256 + kt + kq];
    float4 scv = *(const float4*)&sc[b * 256 + kt + kq];
    float4 shv = *(const float4*)&sh[b * 256 + kt + kq];
    float y0 = fmaf(scv.x, xv.x, shv.x); y0 = y0 >= 0.f ? y0 : 0.01f * y0;
    float y1 = fmaf(scv.y, xv.y, shv.y); y1 = y1 >= 0.f ? y1 : 0.01f * y1;
    float y2 = fmaf(scv.z, xv.z, shv.z); y2 = y2 >= 0.f ? y2 : 0.01f * y2;
    float y3 = fmaf(scv.w, xv.w, shv.w); y3 = y3 >= 0.f ? y3 : 0.01f * y3;
    Xs[kq + 0][rld] = y0; Xs[kq + 1][rld] = y1;
    Xs[kq + 2][rld] = y2; Xs[kq + 3][rld] = y3;
    // stage W: 512 float4s, consecutive lanes -> consecutive 16B (conflict-free)
    #pragma unroll
    for (int it = 0; it < 2; ++it) {
      int idx = it * 256 + tid;          // 0..511
      int k = idx >> 5;                  // 0..15
      int c4 = (idx & 31) * 4;           // 0..124
      *(float4*)&Ws[k][c4] = *(const float4*)&W[(size_t)(kt + k) * 128 + c4];
    }
    __syncthreads();
    #pragma unroll
    for (int k = 0; k < 16; ++k) {
      float xr[4];
      #pragma unroll
      for (int i = 0; i < 4; ++i) xr[i] = Xs[k][ty * 4 + i];
      float4 w0 = *(const float4*)&Ws[k][tx * 4];
      float4 w1 = *(const float4*)&Ws[k][64 + tx * 4];
      float wr[8] = {w0.x, w0.y, w0.z, w0.w, w1.x, w1.y, w1.z, w1.w};
      #pragma unroll
      for (int i = 0; i < 4; ++i)
        #pragma unroll
        for (int j = 0; j < 8; ++j) acc[i][j] = fmaf(xr[i], wr[j], acc[i][j]);
    }
    __syncthreads();
  }

  float av0[4], rv0[4], av1[4], rv1[4];
  #pragma unroll
  for (int j = 0; j < 4; ++j) {
    av0[j] = al[tx * 4 + j];      rv0[j] = ar[tx * 4 + j];
    av1[j] = al[64 + tx * 4 + j]; rv1[j] = ar[64 + tx * 4 + j];
  }
  #pragma unroll
  for (int i = 0; i < 4; ++i) {
    int row = row0 + ty * 4 + i;
    *(float4*)&F[(size_t)row * 128 + tx * 4] =
        make_float4(acc[i][0], acc[i][1], acc[i][2], acc[i][3]);
    *(float4*)&F[(size_t)row * 128 + 64 + tx * 4] =
        make_float4(acc[i][4], acc[i][5], acc[i][6], acc[i][7]);
    float pl0 = 0.f, pr0 = 0.f, pl1 = 0.f, pr1 = 0.f;
    #pragma unroll
    for (int j = 0; j < 4; ++j) {
      pl0 = fmaf(acc[i][j], av0[j], pl0);     pr0 = fmaf(acc[i][j], rv0[j], pr0);
      pl1 = fmaf(acc[i][j + 4], av1[j], pl1); pr1 = fmaf(acc[i][j + 4], rv1[j], pr1);
    }
    #pragma unroll
    for (int off = 1; off < 16; off <<= 1) {
      pl0 += __shfl_xor(pl0, off, 64); pr0 += __shfl_xor(pr0, off, 64);
      pl1 += __shfl_xor(pl1, off, 64); pr1 += __shfl_xor(pr1, off, 64);
    }
    if (tx == 0) {
      el[row * 2 + 0] = pl0; el[row * 2 + 1] = pl1;
      er[row * 2 + 0] = pr0; er[row * 2 + 1] = pr1;
    }
  }
}

// ---------------- GAT edge-softmax + aggregation (wave per dst) ----------------
template <int H>
__device__ inline void load_ev(const float* __restrict__ el, int s, float* ev) {
  if constexpr (H == 4) {
    float4 t = *(const float4*)(el + (size_t)s * 4);
    ev[0] = t.x; ev[1] = t.y; ev[2] = t.z; ev[3] = t.w;
  } else {
    float2 t = *(const float2*)(el + (size_t)s * 2);
    ev[0] = t.x; ev[1] = t.y;
  }
}

template <int H>
__global__ __launch_bounds__(256) void gat_agg(
    const float* __restrict__ F, const float* __restrict__ el,
    const float* __restrict__ er, const int* __restrict__ rowptr,
    const int* __restrict__ csrsrc, float* __restrict__ out) {
  __shared__ float plds[4][64][H];
  __shared__ int slds[4][64];
  const int wave = threadIdx.x >> 6;
  const int lane = threadIdx.x & 63;
  const int wg = blockIdx.x;
  const int xcd = wg & 7, pos = wg >> 3;
  const int g = xcd + (pos >> 8) * 8;
  const int n = g * NPERG + (pos & 255) * 4 + wave;
  const int beg = rowptr[n], end = rowptr[n + 1];
  const int hsel = (H == 4) ? (lane >> 4) : (lane >> 5);

  float erh[H];
  #pragma unroll
  for (int h = 0; h < H; ++h) erh[h] = er[n * H + h];

  float accv[H], psum[H];
  #pragma unroll
  for (int h = 0; h < H; ++h) { accv[h] = 0.f; psum[h] = 0.f; }

  for (int cbeg = beg; cbeg < end; cbeg += 64) {
    int cnt = end - cbeg;
    if (cnt > 64) cnt = 64;
    float pv[H];
    int s = 0;
    #pragma unroll
    for (int h = 0; h < H; ++h) pv[h] = 0.f;
    if (lane < cnt) {
      s = csrsrc[cbeg + lane];
      float ev[H];
      load_ev<H>(el, s, ev);
      #pragma unroll
      for (int h = 0; h < H; ++h) {
        float e = ev[h] + erh[h];
        e = e >= 0.f ? e : 0.2f * e;
        pv[h] = __expf(e);
      }
    }
    #pragma unroll
    for (int h = 0; h < H; ++h) psum[h] += wave_reduce_sum(pv[h]);
    slds[wave][lane] = s;
    if constexpr (H == 4)
      *(float4*)&plds[wave][lane][0] = make_float4(pv[0], pv[1], pv[2], pv[3]);
    else
      *(float2*)&plds[wave][lane][0] = make_float2(pv[0], pv[1]);
    __builtin_amdgcn_s_waitcnt(0);  // lgkmcnt(0): LDS writes visible to this wave

    int j = 0;
    for (; j + 4 <= cnt; j += 4) {
      int ss0 = slds[wave][j + 0], ss1 = slds[wave][j + 1];
      int ss2 = slds[wave][j + 2], ss3 = slds[wave][j + 3];
      float pb0 = plds[wave][j + 0][hsel], pb1 = plds[wave][j + 1][hsel];
      float pb2 = plds[wave][j + 2][hsel], pb3 = plds[wave][j + 3][hsel];
      if constexpr (H == 4) {
        float4 f0 = *(const float4*)&F[(size_t)ss0 * 256 + lane * 4];
        float4 f1 = *(const float4*)&F[(size_t)ss1 * 256 + lane * 4];
        float4 f2 = *(const float4*)&F[(size_t)ss2 * 256 + lane * 4];
        float4 f3 = *(const float4*)&F[(size_t)ss3 * 256 + lane * 4];
        accv[0] = fmaf(pb0, f0.x, accv[0]); accv[1] = fmaf(pb0, f0.y, accv[1]);
        accv[2] = fmaf(pb0, f0.z, accv[2]); accv[3] = fmaf(pb0, f0.w, accv[3]);
        accv[0] = fmaf(pb1, f1.x, accv[0]); accv[1] = fmaf(pb1, f1.y, accv[1]);
        accv[2] = fmaf(pb1, f1.z, accv[2]); accv[3] = fmaf(pb1, f1.w, accv[3]);
        accv[0] = fmaf(pb2, f2.x, accv[0]); accv[1] = fmaf(pb2, f2.y, accv[1]);
        accv[2] = fmaf(pb2, f2.z, accv[2]); accv[3] = fmaf(pb2, f2.w, accv[3]);
        accv[0] = fmaf(pb3, f3.x, accv[0]); accv[1] = fmaf(pb3, f3.y, accv[1]);
        accv[2] = fmaf(pb3, f3.z, accv[2]); accv[3] = fmaf(pb3, f3.w, accv[3]);
      } else {
        float2 f0 = *(const float2*)&F[(size_t)ss0 * 128 + lane * 2];
        float2 f1 = *(const float2*)&F[(size_t)ss1 * 128 + lane * 2];
        float2 f2 = *(const float2*)&F[(size_t)ss2 * 128 + lane * 2];
        float2 f3 = *(const float2*)&F[(size_t)ss3 * 128 + lane * 2];
        accv[0] = fmaf(pb0, f0.x, accv[0]); accv[1] = fmaf(pb0, f0.y, accv[1]);
        accv[0] = fmaf(pb1, f1.x, accv[0]); accv[1] = fmaf(pb1, f1.y, accv[1]);
        accv[0] = fmaf(pb2, f2.x, accv[0]); accv[1] = fmaf(pb2, f2.y, accv[1]);
        accv[0] = fmaf(pb3, f3.x, accv[0]); accv[1] = fmaf(pb3, f3.y, accv[1]);
      }
    }
    for (; j < cnt; ++j) {
      int ss = slds[wave][j];
      float pb = plds[wave][j][hsel];
      if constexpr (H == 4) {
        float4 fv = *(const float4*)&F[(size_t)ss * 256 + lane * 4];
        accv[0] = fmaf(pb, fv.x, accv[0]); accv[1] = fmaf(pb, fv.y, accv[1]);
        accv[2] = fmaf(pb, fv.z, accv[2]); accv[3] = fmaf(pb, fv.w, accv[3]);
      } else {
        float2 fv = *(const float2*)&F[(size_t)ss * 128 + lane * 2];
        accv[0] = fmaf(pb, fv.x, accv[0]); accv[1] = fmaf(pb, fv.y, accv[1]);
      }
    }
  }

  float z;
  if constexpr (H == 4)
    z = hsel == 0 ? psum[0] : hsel == 1 ? psum[1] : hsel == 2 ? psum[2] : psum[3];
  else
    z = hsel == 0 ? psum[0] : psum[1];
  float inv = 1.0f / fmaxf(z, 1e-9f);
  if constexpr (H == 4) {
    float4 o = make_float4(accv[0] * inv, accv[1] * inv, accv[2] * inv, accv[3] * inv);
    *(float4*)&out[(size_t)n * 256 + lane * 4] = o;
  } else {
    float2 o = make_float2(accv[0] * inv, accv[1] * inv);
    *(float2*)&out[(size_t)n * 128 + lane * 2] = o;
  }
}

// ---------------- GraphNorm ----------------
template <int C>
__global__ void gn_stats_partial(const float* __restrict__ X, float* __restrict__ ps,
                                 float* __restrict__ ps2) {
  const int id = blockIdx.x;
  const int xcd = id & 7, pos = id >> 3;
  const int b = xcd + (pos >> 4) * 8;
  const int sgm = pos & 15;
  int ch = threadIdx.x;
  const float* p = X + ((size_t)b * NPERG + sgm * 64) * C + ch;
  float sx = 0.f, sx2 = 0.f;
  for (int i = 0; i < 64; ++i) { float x = p[(size_t)i * C]; sx += x; sx2 += x * x; }
  ps[(b * 16 + sgm) * C + ch] = sx;
  ps2[(b * 16 + sgm) * C + ch] = sx2;
}

template <int C>
__global__ void gn_stats_final(const float* __restrict__ ps, const float* __restrict__ ps2,
                               const float* __restrict__ alpha, const float* __restrict__ gamma,
                               const float* __restrict__ beta, float* __restrict__ scale,
                               float* __restrict__ shift) {
  int b = blockIdx.x, ch = threadIdx.x;
  float sx = 0.f, sx2 = 0.f;
  for (int s = 0; s < 16; ++s) { sx += ps[(b * 16 + s) * C + ch]; sx2 += ps2[(b * 16 + s) * C + ch]; }
  const float inv = 1.0f / (float)NPERG;
  float mu = sx * inv;
  int d = ch & 63;
  float a = alpha[d];
  float var = sx2 * inv - mu * mu * a * (2.f - a);
  float sc = gamma[d] / sqrtf(var + 1e-5f);
  scale[b * C + ch] = sc;
  shift[b * C + ch] = beta[d] - sc * a * mu;
}

// keys-only: key[n] = max_d( (1/H) sum_h leaky(sc*h + sh) )
template <int C, int H>
__global__ void gn_keys(const float* __restrict__ X, const float* __restrict__ scale,
                        const float* __restrict__ shift, float* __restrict__ keyb) {
  const int wg = blockIdx.x;                       // NNODES/4
  const int xcd = wg & 7, pos = wg >> 3;
  const int g = xcd + (pos >> 8) * 8;
  const int n = g * NPERG + (pos & 255) * 4 + (threadIdx.x >> 6);
  const int d = threadIdx.x & 63;
  const int b = g;
  float s = 0.f;
  #pragma unroll
  for (int h = 0; h < H; ++h) {
    int ch = h * 64 + d;
    float y = fmaf(scale[b * C + ch], X[(size_t)n * C + ch], shift[b * C + ch]);
    y = y >= 0.f ? y : 0.01f * y;
    s += y;
  }
  float key = wave_reduce_max(s * (1.0f / H));
  if (d == 0) keyb[n] = key;
}

// ---------------- SortPooling (fused topk + gather + row-sort) ----------------
__device__ inline float bitonic_sort64(float v, int lane) {
  #pragma unroll
  for (int kk = 2; kk <= 64; kk <<= 1) {
    #pragma unroll
    for (int j = kk >> 1; j > 0; j >>= 1) {
      float o = __shfl_xor(v, j, 64);
      bool lower = (lane & j) == 0;
      bool asc = (lane & kk) == 0;
      v = (lower == asc) ? fminf(v, o) : fmaxf(v, o);
    }
  }
  return v;
}

__device__ inline void bitonic_sort1024(unsigned long long& v,
                                        unsigned long long* lds, int tid) {
  for (int kk = 2; kk <= NPERG; kk <<= 1) {
    for (int j = kk >> 1; j > 0; j >>= 1) {
      unsigned long long o;
      if (j >= 64) {
        lds[tid] = v;
        __syncthreads();
        o = lds[tid ^ j];
        __syncthreads();
      } else {
        o = __shfl_xor(v, j, 64);
      }
      bool lower = (tid & j) == 0;
      bool desc = (tid & kk) == 0;
      unsigned long long mx = v > o ? v : o;
      unsigned long long mn = v > o ? o : v;
      v = (lower == desc) ? mx : mn;
    }
  }
  lds[tid] = v;
  __syncthreads();
}

__device__ inline unsigned long long pack_key(float f, int tid) {
  unsigned int u = __float_as_uint(f);
  u = (u & 0x80000000u) ? ~u : (u | 0x80000000u);   // order-preserving map
  return ((unsigned long long)u << 32) | (unsigned int)(NPERG - 1 - tid);
}

// layer-1: sort keys; 16 waves normalize+mean+sort the 32 selected h1 rows.
__global__ __launch_bounds__(1024) void topk_pool1(const float* __restrict__ keyb,
                                                   const float* __restrict__ h1,
                                                   const float* __restrict__ scale,
                                                   const float* __restrict__ shift,
                                                   float* __restrict__ r) {
  __shared__ unsigned long long lds[NPERG];
  const int b = blockIdx.x, tid = threadIdx.x;
  unsigned long long v = pack_key(keyb[b * NPERG + tid], tid);
  bitonic_sort1024(v, lds, tid);
  const int wave = tid >> 6, lane = tid & 63;
  #pragma unroll
  for (int q = 0; q < 2; ++q) {
    int rank = wave * 2 + q;
    int node = (int)(NPERG - 1 - (unsigned int)(lds[rank] & 0xFFFFFFFFu));
    size_t base = ((size_t)(b * NPERG + node)) * 256;
    float s = 0.f;
    #pragma unroll
    for (int h = 0; h < 4; ++h) {
      int ch = h * 64 + lane;
      float y = fmaf(scale[b * 256 + ch], h1[base + ch], shift[b * 256 + ch]);
      y = y >= 0.f ? y : 0.01f * y;
      s += y;
    }
    float val = bitonic_sort64(0.25f * s, lane);
    r[(size_t)b * 4096 + rank * 64 + lane] = val;
  }
}

// layer-2: same with h2 (C=128, H=2), writes at +2048.
__global__ __launch_bounds__(1024) void topk_pool2(const float* __restrict__ keyb,
                                                   const float* __restrict__ h2,
                                                   const float* __restrict__ scale,
                                                   const float* __restrict__ shift,
                                                   float* __restrict__ r) {
  __shared__ unsigned long long lds[NPERG];
  const int b = blockIdx.x, tid = threadIdx.x;
  unsigned long long v = pack_key(keyb[b * NPERG + tid], tid);
  bitonic_sort1024(v, lds, tid);
  const int wave = tid >> 6, lane = tid & 63;
  #pragma unroll
  for (int q = 0; q < 2; ++q) {
    int rank = wave * 2 + q;
    int node = (int)(NPERG - 1 - (unsigned int)(lds[rank] & 0xFFFFFFFFu));
    size_t base = ((size_t)(b * NPERG + node)) * 128;
    float s = 0.f;
    #pragma unroll
    for (int h = 0; h < 2; ++h) {
      int ch = h * 64 + lane;
      float y = fmaf(scale[b * 128 + ch], h2[base + ch], shift[b * 128 + ch]);
      y = y >= 0.f ? y : 0.01f * y;
      s += y;
    }
    float val = bitonic_sort64(0.5f * s, lane);
    r[(size_t)b * 4096 + 2048 + rank * 64 + lane] = val;
  }
}

// ---------------- FC head ----------------
__global__ __launch_bounds__(256) void fc1_partial(const float* __restrict__ r,
                                                   const float* __restrict__ w,
                                                   float* __restrict__ part) {
  __shared__ float rs_t[64][36];   // [k][m]
  const int ks = blockIdx.x, nb = blockIdx.y;
  const int tid = threadIdx.x;
  const int tx = tid & 63;
  const int ty = tid >> 6;

  #pragma unroll
  for (int t = 0; t < 8; ++t) {
    int elem = t * 256 + tid;
    int m = elem >> 6, k = elem & 63;
    rs_t[k][m] = r[(size_t)m * 4096 + ks * 64 + k];
  }
  __syncthreads();

  const float* wp = w + (size_t)(ks * 64) * 2048 + nb * 256 + tx * 4;
  float4 acc[8];
  #pragma unroll
  for (int i = 0; i < 8; ++i) acc[i] = make_float4(0.f, 0.f, 0.f, 0.f);

  #pragma unroll 4
  for (int k = 0; k < 64; ++k) {
    float4 wv = *(const float4*)&wp[(size_t)k * 2048];
    float4 ra = *(const float4*)&rs_t[k][ty * 8];
    float4 rb = *(const float4*)&rs_t[k][ty * 8 + 4];
    float rr[8] = {ra.x, ra.y, ra.z, ra.w, rb.x, rb.y, rb.z, rb.w};
    #pragma unroll
    for (int i = 0; i < 8; ++i) {
      acc[i].x = fmaf(rr[i], wv.x, acc[i].x);
      acc[i].y = fmaf(rr[i], wv.y, acc[i].y);
      acc[i].z = fmaf(rr[i], wv.z, acc[i].z);
      acc[i].w = fmaf(rr[i], wv.w, acc[i].w);
    }
  }

  #pragma unroll
  for (int i = 0; i < 8; ++i) {
    int m = ty * 8 + i;
    *(float4*)&part[((size_t)ks * 32 + m) * 2048 + nb * 256 + tx * 4] = acc[i];
  }
}

__global__ __launch_bounds__(256) void fc1_reduce(const float* __restrict__ part,
                                                  const float* __restrict__ bias,
                                                  float* __restrict__ hidden) {
  int idx = blockIdx.x * 256 + threadIdx.x;  // 32*512 (m, n4)
  int m = idx >> 9, n4 = idx & 511;
  const float* pp = part + (size_t)m * 2048 + n4 * 4;
  float4 b4 = *(const float4*)&bias[n4 * 4];
  float4 s = b4;
  #pragma unroll 8
  for (int ks = 0; ks < FC1_KS; ++ks) {
    float4 v = *(const float4*)&pp[(size_t)ks * 32 * 2048];
    s.x += v.x; s.y += v.y; s.z += v.z; s.w += v.w;
  }
  s.x = fmaxf(s.x, 0.f); s.y = fmaxf(s.y, 0.f);
  s.z = fmaxf(s.z, 0.f); s.w = fmaxf(s.w, 0.f);
  *(float4*)&hidden[(size_t)m * 2048 + n4 * 4] = s;
}

__global__ void fc2_kernel(const float* __restrict__ hidden, const float* __restrict__ w,
                           const float* __restrict__ bias, float* __restrict__ out) {
  int wid = (blockIdx.x * blockDim.x + threadIdx.x) >> 6;  // 512 waves
  int lane = threadIdx.x & 63;
  int m = wid >> 4, o = wid & 15;
  float s = 0.f;
  for (int k = lane; k < 2048; k += 64) s = fmaf(hidden[(size_t)m * 2048 + k], w[k * 16 + o], s);
  s = wave_reduce_sum(s);
  if (lane == 0) out[m * 16 + o] = s + bias[o];
}

// ---------------- launch ----------------
extern "C" void kernel_launch(void* const* d_in, const int* in_sizes, int n_in,
                              void* d_out, int out_size, void* d_ws, size_t ws_size,
                              hipStream_t stream) {
  const float* features = (const float*)d_in[0];
  const int* src = (const int*)d_in[1];
  const int* dst = (const int*)d_in[2];
  const float* W1 = (const float*)d_in[3];
  const float* al1 = (const float*)d_in[4];
  const float* ar1 = (const float*)d_in[5];
  const float* W2 = (const float*)d_in[6];
  const float* al2 = (const float*)d_in[7];
  const float* ar2 = (const float*)d_in[8];
  const float* gn1a = (const float*)d_in[9];
  const float* gn1g = (const float*)d_in[10];
  const float* gn1b = (const float*)d_in[11];
  const float* gn2a = (const float*)d_in[12];
  const float* gn2g = (const float*)d_in[13];
  const float* gn2b = (const float*)d_in[14];
  const float* fc1w = (const float*)d_in[15];
  const float* fc1b = (const float*)d_in[16];
  const float* fc2w = (const float*)d_in[17];
  const float* fc2b = (const float*)d_in[18];
  float* out = (float*)d_out;
  const int E_ = in_sizes[1];

  float* ws = (float*)d_ws;
  size_t off = 0;
  float* A = ws + off;      off += (size_t)NNODES * 256;  // f1 | (f2, h2) | fc1 part
  float* Bb = ws + off;     off += (size_t)NNODES * 256;  // h1 | hidden
  float* el1 = ws + off;    off += (size_t)NNODES * 4;
  float* er1 = ws + off;    off += (size_t)NNODES * 4;
  float* el2 = ws + off;    off += (size_t)NNODES * 2;
  float* er2 = ws + off;    off += (size_t)NNODES * 2;
  float* sc1 = ws + off;    off += 32 * 256;
  float* sh1 = ws + off;    off += 32 * 256;
  float* sc2 = ws + off;    off += 32 * 128;
  float* sh2 = ws + off;    off += 32 * 128;
  float* ps = ws + off;     off += 32 * 16 * 256;
  float* ps2 = ws + off;    off += 32 * 16 * 256;
  float* rbuf = ws + off;   off += 32 * 4096;
  float* keyb = ws + off;   off += NNODES;
  int* ibase = (int*)(ws + off);
  int* counts = ibase;
  int* rowptr = counts + NNODES;
  int* cursor = rowptr + NNODES + 1;
  int* csrsrc = cursor + NNODES;

  float* f1 = A;
  float* h1 = Bb;
  float* f2 = A;                                    // f1 dead after gat_agg<4>
  float* h2 = A + (size_t)NNODES * 128;
  float* part = A;                                  // f2 dead after gat_agg<2>
  float* hidden = Bb;                               // h1 dead after gemm2/topk_pool1

  hipMemsetAsync(counts, 0, NNODES * sizeof(int), stream);
  csr_count<<<(E_ + 255) / 256, 256, 0, stream>>>(dst, counts, E_);
  csr_scan<<<1, 1024, 0, stream>>>(counts, rowptr, cursor);
  csr_fill<<<(E_ + 255) / 256, 256, 0, stream>>>(src, dst, cursor, csrsrc, E_);

  dim3 g1(NNODES / 64, 4);
  gemm_fused<64, 256, 4><<<g1, 256, 0, stream>>>(features, W1, al1, ar1, f1, el1, er1);
  gat_agg<4><<<NNODES / 4, 256, 0, stream>>>(f1, el1, er1, rowptr, csrsrc, h1);

  gn_stats_partial<256><<<NGRAPH * 16, 256, 0, stream>>>(h1, ps, ps2);
  gn_stats_final<256><<<NGRAPH, 256, 0, stream>>>(ps, ps2, gn1a, gn1g, gn1b, sc1, sh1);
  gn_keys<256, 4><<<NNODES / 4, 256, 0, stream>>>(h1, sc1, sh1, keyb);

  topk_pool1<<<NGRAPH, 1024, 0, stream>>>(keyb, h1, sc1, sh1, rbuf);

  gemm2_fused<<<NNODES / 64, 256, 0, stream>>>(h1, sc1, sh1, W2, al2, ar2, f2, el2, er2);
  gat_agg<2><<<NNODES / 4, 256, 0, stream>>>(f2, el2, er2, rowptr, csrsrc, h2);

  gn_stats_partial<128><<<NGRAPH * 16, 128, 0, stream>>>(h2, ps, ps2);
  gn_stats_final<128><<<NGRAPH, 128, 0, stream>>>(ps, ps2, gn2a, gn2g, gn2b, sc2, sh2);
  gn_keys<128, 2><<<NNODES / 4, 256, 0, stream>>>(h2, sc2, sh2, keyb);

  topk_pool2<<<NGRAPH, 1024, 0, stream>>>(keyb, h2, sc2, sh2, rbuf);

  dim3 gfc(FC1_KS, 8);
  fc1_partial<<<gfc, 256, 0, stream>>>(rbuf, fc1w, part);
  fc1_reduce<<<32 * 2048 / 1024, 256, 0, stream>>>(part, fc1b, hidden);
  fc2_kernel<<<128, 256, 0, stream>>>(hidden, fc2w, fc2b, out);
}

// Round 13
// 254.906 us; speedup vs baseline: 1.0150x; 1.0150x over previous
//
#include <hip/hip_runtime.h>
#include <math.h>

#define NNODES 32768
#define NGRAPH 32
#define NPERG  1024
#define KSEL   32
#define FC1_KS 64   // split-K chunks for fc1 (kc = 4096/64 = 64)

__device__ inline float wave_reduce_sum(float v) {
  #pragma unroll
  for (int off = 32; off > 0; off >>= 1) v += __shfl_xor(v, off, 64);
  return v;
}
__device__ inline float wave_reduce_max(float v) {
  #pragma unroll
  for (int off = 32; off > 0; off >>= 1) v = fmaxf(v, __shfl_xor(v, off, 64));
  return v;
}

// ---------------- CSR build ----------------
__global__ void csr_count(const int* __restrict__ dst, int* __restrict__ counts, int E_) {
  int e = blockIdx.x * 256 + threadIdx.x;
  if (e < E_) atomicAdd(&counts[dst[e]], 1);
}

__global__ __launch_bounds__(1024) void csr_scan(const int* __restrict__ counts,
                                                 int* __restrict__ rowptr,
                                                 int* __restrict__ cursor) {
  __shared__ int partial[1024];
  const int tid = threadIdx.x;
  const int base = tid * 32;
  int c[32];
  int s = 0;
  #pragma unroll
  for (int i = 0; i < 32; ++i) { c[i] = counts[base + i]; s += c[i]; }
  partial[tid] = s;
  __syncthreads();
  for (int off = 1; off < 1024; off <<= 1) {
    int t = (tid >= off) ? partial[tid - off] : 0;
    __syncthreads();
    partial[tid] += t;
    __syncthreads();
  }
  int run = partial[tid] - s;  // exclusive prefix
  #pragma unroll
  for (int i = 0; i < 32; ++i) {
    rowptr[base + i] = run;
    cursor[base + i] = run;
    run += c[i];
  }
  if (tid == 1023) rowptr[NNODES] = run;
}

__global__ void csr_fill(const int* __restrict__ src, const int* __restrict__ dst,
                         int* __restrict__ cursor, int* __restrict__ csrsrc, int E_) {
  int e = blockIdx.x * 256 + threadIdx.x;
  if (e < E_) {
    int p = atomicAdd(&cursor[dst[e]], 1);
    csrsrc[p] = src[e];
  }
}

// ---------------- Layer-1 GEMM + fused attention terms (proven, unchanged) ----------------
template <int K, int C, int H>
__global__ __launch_bounds__(256) void gemm_fused(
    const float* __restrict__ X, const float* __restrict__ W,
    const float* __restrict__ al, const float* __restrict__ ar,
    float* __restrict__ F, float* __restrict__ el, float* __restrict__ er) {
  __shared__ float Xs[16][68];
  __shared__ float Ws[16][64];
  __shared__ float redl[64][16];
  __shared__ float redr[64][16];
  const int tid = threadIdx.x;
  const int tx = tid & 15, ty = tid >> 4;
  const int bx = blockIdx.x;
  const int xcd = bx & 7, pos = bx >> 3;
  const int gph = xcd + (pos >> 4) * 8;
  const int row0 = (gph * 16 + (pos & 15)) * 64;
  const int col0 = blockIdx.y * 64;

  float acc[4][4];
  #pragma unroll
  for (int i = 0; i < 4; ++i)
    #pragma unroll
    for (int j = 0; j < 4; ++j) acc[i][j] = 0.f;

  const int rld = tid >> 2;
  const int kq = (tid & 3) * 4;
  const int kw = tid >> 4;
  const int cw = (tid & 15) * 4;

  for (int kt = 0; kt < K; kt += 16) {
    float4 xv = *(const float4*)&X[(size_t)(row0 + rld) * K + kt + kq];
    Xs[kq + 0][rld] = xv.x; Xs[kq + 1][rld] = xv.y;
    Xs[kq + 2][rld] = xv.z; Xs[kq + 3][rld] = xv.w;
    *(float4*)&Ws[kw][cw] = *(const float4*)&W[(size_t)(kt + kw) * C + col0 + cw];
    __syncthreads();
    #pragma unroll
    for (int k = 0; k < 16; ++k) {
      float xr[4], wr[4];
      #pragma unroll
      for (int i = 0; i < 4; ++i) xr[i] = Xs[k][ty * 4 + i];
      #pragma unroll
      for (int j = 0; j < 4; ++j) wr[j] = Ws[k][tx * 4 + j];
      #pragma unroll
      for (int i = 0; i < 4; ++i)
        #pragma unroll
        for (int j = 0; j < 4; ++j) acc[i][j] = fmaf(xr[i], wr[j], acc[i][j]);
    }
    __syncthreads();
  }

  float av[4], rv[4];
  #pragma unroll
  for (int j = 0; j < 4; ++j) { av[j] = al[col0 + tx * 4 + j]; rv[j] = ar[col0 + tx * 4 + j]; }
  #pragma unroll
  for (int i = 0; i < 4; ++i) {
    float4 o = make_float4(acc[i][0], acc[i][1], acc[i][2], acc[i][3]);
    *(float4*)&F[(size_t)(row0 + ty * 4 + i) * C + col0 + tx * 4] = o;
    float pl = acc[i][0] * av[0] + acc[i][1] * av[1] + acc[i][2] * av[2] + acc[i][3] * av[3];
    float pr = acc[i][0] * rv[0] + acc[i][1] * rv[1] + acc[i][2] * rv[2] + acc[i][3] * rv[3];
    redl[ty * 4 + i][tx] = pl;
    redr[ty * 4 + i][tx] = pr;
  }
  __syncthreads();
  if (tid < 64) {
    float s = 0.f, t = 0.f;
    #pragma unroll
    for (int x = 0; x < 16; ++x) { s += redl[tid][x]; t += redr[tid][x]; }
    el[(row0 + tid) * H + blockIdx.y] = s;
    er[(row0 + tid) * H + blockIdx.y] = t;
  }
}

// ---------------- Layer-2 GEMM: proven 64x64 tiling + normalize-on-load ----------------
// grid (NNODES/64, 2): 1024 blocks. X = h1 raw; leaky(sc*x+sh) applied on staging.
__global__ __launch_bounds__(256) void gemm2_fused(
    const float* __restrict__ X, const float* __restrict__ sc,
    const float* __restrict__ sh, const float* __restrict__ W,
    const float* __restrict__ al, const float* __restrict__ ar,
    float* __restrict__ F, float* __restrict__ el, float* __restrict__ er) {
  __shared__ float Xs[16][68];
  __shared__ float Ws[16][64];
  __shared__ float redl[64][16];
  __shared__ float redr[64][16];
  const int tid = threadIdx.x;
  const int tx = tid & 15, ty = tid >> 4;
  const int bx = blockIdx.x;
  const int xcd = bx & 7, pos = bx >> 3;
  const int gph = xcd + (pos >> 4) * 8;
  const int row0 = (gph * 16 + (pos & 15)) * 64;
  const int col0 = blockIdx.y * 64;
  const int b = gph;

  float acc[4][4];
  #pragma unroll
  for (int i = 0; i < 4; ++i)
    #pragma unroll
    for (int j = 0; j < 4; ++j) acc[i][j] = 0.f;

  const int rld = tid >> 2;
  const int kq = (tid & 3) * 4;
  const int kw = tid >> 4;
  const int cw = (tid & 15) * 4;

  for (int kt = 0; kt < 256; kt += 16) {
    float4 xv = *(const float4*)&X[(size_t)(row0 + rld) * 256 + kt + kq];
    float4 scv = *(const float4*)&sc[b * 256 + kt + kq];
    float4 shv = *(const float4*)&sh[b * 256 + kt + kq];
    float y0 = fmaf(scv.x, xv.x, shv.x); y0 = y0 >= 0.f ? y0 : 0.01f * y0;
    float y1 = fmaf(scv.y, xv.y, shv.y); y1 = y1 >= 0.f ? y1 : 0.01f * y1;
    float y2 = fmaf(scv.z, xv.z, shv.z); y2 = y2 >= 0.f ? y2 : 0.01f * y2;
    float y3 = fmaf(scv.w, xv.w, shv.w); y3 = y3 >= 0.f ? y3 : 0.01f * y3;
    Xs[kq + 0][rld] = y0; Xs[kq + 1][rld] = y1;
    Xs[kq + 2][rld] = y2; Xs[kq + 3][rld] = y3;
    *(float4*)&Ws[kw][cw] = *(const float4*)&W[(size_t)(kt + kw) * 128 + col0 + cw];
    __syncthreads();
    #pragma unroll
    for (int k = 0; k < 16; ++k) {
      float xr[4], wr[4];
      #pragma unroll
      for (int i = 0; i < 4; ++i) xr[i] = Xs[k][ty * 4 + i];
      #pragma unroll
      for (int j = 0; j < 4; ++j) wr[j] = Ws[k][tx * 4 + j];
      #pragma unroll
      for (int i = 0; i < 4; ++i)
        #pragma unroll
        for (int j = 0; j < 4; ++j) acc[i][j] = fmaf(xr[i], wr[j], acc[i][j]);
    }
    __syncthreads();
  }

  float av[4], rv[4];
  #pragma unroll
  for (int j = 0; j < 4; ++j) { av[j] = al[col0 + tx * 4 + j]; rv[j] = ar[col0 + tx * 4 + j]; }
  #pragma unroll
  for (int i = 0; i < 4; ++i) {
    float4 o = make_float4(acc[i][0], acc[i][1], acc[i][2], acc[i][3]);
    *(float4*)&F[(size_t)(row0 + ty * 4 + i) * 128 + col0 + tx * 4] = o;
    float pl = acc[i][0] * av[0] + acc[i][1] * av[1] + acc[i][2] * av[2] + acc[i][3] * av[3];
    float pr = acc[i][0] * rv[0] + acc[i][1] * rv[1] + acc[i][2] * rv[2] + acc[i][3] * rv[3];
    redl[ty * 4 + i][tx] = pl;
    redr[ty * 4 + i][tx] = pr;
  }
  __syncthreads();
  if (tid < 64) {
    float s = 0.f, t = 0.f;
    #pragma unroll
    for (int x = 0; x < 16; ++x) { s += redl[tid][x]; t += redr[tid][x]; }
    el[(row0 + tid) * 2 + blockIdx.y] = s;
    er[(row0 + tid) * 2 + blockIdx.y] = t;
  }
}

// ---------------- GAT edge-softmax + aggregation (wave per dst) ----------------
template <int H>
__device__ inline void load_ev(const float* __restrict__ el, int s, float* ev) {
  if constexpr (H == 4) {
    float4 t = *(const float4*)(el + (size_t)s * 4);
    ev[0] = t.x; ev[1] = t.y; ev[2] = t.z; ev[3] = t.w;
  } else {
    float2 t = *(const float2*)(el + (size_t)s * 2);
    ev[0] = t.x; ev[1] = t.y;
  }
}

template <int H>
__global__ __launch_bounds__(256) void gat_agg(
    const float* __restrict__ F, const float* __restrict__ el,
    const float* __restrict__ er, const int* __restrict__ rowptr,
    const int* __restrict__ csrsrc, float* __restrict__ out) {
  __shared__ float plds[4][64][H];
  __shared__ int slds[4][64];
  const int wave = threadIdx.x >> 6;
  const int lane = threadIdx.x & 63;
  const int wg = blockIdx.x;
  const int xcd = wg & 7, pos = wg >> 3;
  const int g = xcd + (pos >> 8) * 8;
  const int n = g * NPERG + (pos & 255) * 4 + wave;
  const int beg = rowptr[n], end = rowptr[n + 1];
  const int hsel = (H == 4) ? (lane >> 4) : (lane >> 5);

  float erh[H];
  #pragma unroll
  for (int h = 0; h < H; ++h) erh[h] = er[n * H + h];

  float accv[H], psum[H];
  #pragma unroll
  for (int h = 0; h < H; ++h) { accv[h] = 0.f; psum[h] = 0.f; }

  for (int cbeg = beg; cbeg < end; cbeg += 64) {
    int cnt = end - cbeg;
    if (cnt > 64) cnt = 64;
    float pv[H];
    int s = 0;
    #pragma unroll
    for (int h = 0; h < H; ++h) pv[h] = 0.f;
    if (lane < cnt) {
      s = csrsrc[cbeg + lane];
      float ev[H];
      load_ev<H>(el, s, ev);
      #pragma unroll
      for (int h = 0; h < H; ++h) {
        float e = ev[h] + erh[h];
        e = e >= 0.f ? e : 0.2f * e;
        pv[h] = __expf(e);
      }
    }
    #pragma unroll
    for (int h = 0; h < H; ++h) psum[h] += wave_reduce_sum(pv[h]);
    slds[wave][lane] = s;
    if constexpr (H == 4)
      *(float4*)&plds[wave][lane][0] = make_float4(pv[0], pv[1], pv[2], pv[3]);
    else
      *(float2*)&plds[wave][lane][0] = make_float2(pv[0], pv[1]);
    __builtin_amdgcn_s_waitcnt(0);  // lgkmcnt(0): LDS writes visible to this wave

    int j = 0;
    for (; j + 4 <= cnt; j += 4) {
      int ss0 = slds[wave][j + 0], ss1 = slds[wave][j + 1];
      int ss2 = slds[wave][j + 2], ss3 = slds[wave][j + 3];
      float pb0 = plds[wave][j + 0][hsel], pb1 = plds[wave][j + 1][hsel];
      float pb2 = plds[wave][j + 2][hsel], pb3 = plds[wave][j + 3][hsel];
      if constexpr (H == 4) {
        float4 f0 = *(const float4*)&F[(size_t)ss0 * 256 + lane * 4];
        float4 f1 = *(const float4*)&F[(size_t)ss1 * 256 + lane * 4];
        float4 f2 = *(const float4*)&F[(size_t)ss2 * 256 + lane * 4];
        float4 f3 = *(const float4*)&F[(size_t)ss3 * 256 + lane * 4];
        accv[0] = fmaf(pb0, f0.x, accv[0]); accv[1] = fmaf(pb0, f0.y, accv[1]);
        accv[2] = fmaf(pb0, f0.z, accv[2]); accv[3] = fmaf(pb0, f0.w, accv[3]);
        accv[0] = fmaf(pb1, f1.x, accv[0]); accv[1] = fmaf(pb1, f1.y, accv[1]);
        accv[2] = fmaf(pb1, f1.z, accv[2]); accv[3] = fmaf(pb1, f1.w, accv[3]);
        accv[0] = fmaf(pb2, f2.x, accv[0]); accv[1] = fmaf(pb2, f2.y, accv[1]);
        accv[2] = fmaf(pb2, f2.z, accv[2]); accv[3] = fmaf(pb2, f2.w, accv[3]);
        accv[0] = fmaf(pb3, f3.x, accv[0]); accv[1] = fmaf(pb3, f3.y, accv[1]);
        accv[2] = fmaf(pb3, f3.z, accv[2]); accv[3] = fmaf(pb3, f3.w, accv[3]);
      } else {
        float2 f0 = *(const float2*)&F[(size_t)ss0 * 128 + lane * 2];
        float2 f1 = *(const float2*)&F[(size_t)ss1 * 128 + lane * 2];
        float2 f2 = *(const float2*)&F[(size_t)ss2 * 128 + lane * 2];
        float2 f3 = *(const float2*)&F[(size_t)ss3 * 128 + lane * 2];
        accv[0] = fmaf(pb0, f0.x, accv[0]); accv[1] = fmaf(pb0, f0.y, accv[1]);
        accv[0] = fmaf(pb1, f1.x, accv[0]); accv[1] = fmaf(pb1, f1.y, accv[1]);
        accv[0] = fmaf(pb2, f2.x, accv[0]); accv[1] = fmaf(pb2, f2.y, accv[1]);
        accv[0] = fmaf(pb3, f3.x, accv[0]); accv[1] = fmaf(pb3, f3.y, accv[1]);
      }
    }
    for (; j < cnt; ++j) {
      int ss = slds[wave][j];
      float pb = plds[wave][j][hsel];
      if constexpr (H == 4) {
        float4 fv = *(const float4*)&F[(size_t)ss * 256 + lane * 4];
        accv[0] = fmaf(pb, fv.x, accv[0]); accv[1] = fmaf(pb, fv.y, accv[1]);
        accv[2] = fmaf(pb, fv.z, accv[2]); accv[3] = fmaf(pb, fv.w, accv[3]);
      } else {
        float2 fv = *(const float2*)&F[(size_t)ss * 128 + lane * 2];
        accv[0] = fmaf(pb, fv.x, accv[0]); accv[1] = fmaf(pb, fv.y, accv[1]);
      }
    }
  }

  float z;
  if constexpr (H == 4)
    z = hsel == 0 ? psum[0] : hsel == 1 ? psum[1] : hsel == 2 ? psum[2] : psum[3];
  else
    z = hsel == 0 ? psum[0] : psum[1];
  float inv = 1.0f / fmaxf(z, 1e-9f);
  if constexpr (H == 4) {
    float4 o = make_float4(accv[0] * inv, accv[1] * inv, accv[2] * inv, accv[3] * inv);
    *(float4*)&out[(size_t)n * 256 + lane * 4] = o;
  } else {
    float2 o = make_float2(accv[0] * inv, accv[1] * inv);
    *(float2*)&out[(size_t)n * 128 + lane * 2] = o;
  }
}

// ---------------- GraphNorm ----------------
template <int C>
__global__ void gn_stats_partial(const float* __restrict__ X, float* __restrict__ ps,
                                 float* __restrict__ ps2) {
  const int id = blockIdx.x;
  const int xcd = id & 7, pos = id >> 3;
  const int b = xcd + (pos >> 4) * 8;
  const int sgm = pos & 15;
  int ch = threadIdx.x;
  const float* p = X + ((size_t)b * NPERG + sgm * 64) * C + ch;
  float sx = 0.f, sx2 = 0.f;
  for (int i = 0; i < 64; ++i) { float x = p[(size_t)i * C]; sx += x; sx2 += x * x; }
  ps[(b * 16 + sgm) * C + ch] = sx;
  ps2[(b * 16 + sgm) * C + ch] = sx2;
}

template <int C>
__global__ void gn_stats_final(const float* __restrict__ ps, const float* __restrict__ ps2,
                               const float* __restrict__ alpha, const float* __restrict__ gamma,
                               const float* __restrict__ beta, float* __restrict__ scale,
                               float* __restrict__ shift) {
  int b = blockIdx.x, ch = threadIdx.x;
  float sx = 0.f, sx2 = 0.f;
  for (int s = 0; s < 16; ++s) { sx += ps[(b * 16 + s) * C + ch]; sx2 += ps2[(b * 16 + s) * C + ch]; }
  const float inv = 1.0f / (float)NPERG;
  float mu = sx * inv;
  int d = ch & 63;
  float a = alpha[d];
  float var = sx2 * inv - mu * mu * a * (2.f - a);
  float sc = gamma[d] / sqrtf(var + 1e-5f);
  scale[b * C + ch] = sc;
  shift[b * C + ch] = beta[d] - sc * a * mu;
}

// keys-only: key[n] = max_d( (1/H) sum_h leaky(sc*h + sh) )
template <int C, int H>
__global__ void gn_keys(const float* __restrict__ X, const float* __restrict__ scale,
                        const float* __restrict__ shift, float* __restrict__ keyb) {
  const int wg = blockIdx.x;                       // NNODES/4
  const int xcd = wg & 7, pos = wg >> 3;
  const int g = xcd + (pos >> 8) * 8;
  const int n = g * NPERG + (pos & 255) * 4 + (threadIdx.x >> 6);
  const int d = threadIdx.x & 63;
  const int b = g;
  float s = 0.f;
  #pragma unroll
  for (int h = 0; h < H; ++h) {
    int ch = h * 64 + d;
    float y = fmaf(scale[b * C + ch], X[(size_t)n * C + ch], shift[b * C + ch]);
    y = y >= 0.f ? y : 0.01f * y;
    s += y;
  }
  float key = wave_reduce_max(s * (1.0f / H));
  if (d == 0) keyb[n] = key;
}

// ---------------- SortPooling (fused topk + gather + row-sort) ----------------
__device__ inline float bitonic_sort64(float v, int lane) {
  #pragma unroll
  for (int kk = 2; kk <= 64; kk <<= 1) {
    #pragma unroll
    for (int j = kk >> 1; j > 0; j >>= 1) {
      float o = __shfl_xor(v, j, 64);
      bool lower = (lane & j) == 0;
      bool asc = (lane & kk) == 0;
      v = (lower == asc) ? fminf(v, o) : fmaxf(v, o);
    }
  }
  return v;
}

__device__ inline void bitonic_sort1024(unsigned long long& v,
                                        unsigned long long* lds, int tid) {
  for (int kk = 2; kk <= NPERG; kk <<= 1) {
    for (int j = kk >> 1; j > 0; j >>= 1) {
      unsigned long long o;
      if (j >= 64) {
        lds[tid] = v;
        __syncthreads();
        o = lds[tid ^ j];
        __syncthreads();
      } else {
        o = __shfl_xor(v, j, 64);
      }
      bool lower = (tid & j) == 0;
      bool desc = (tid & kk) == 0;
      unsigned long long mx = v > o ? v : o;
      unsigned long long mn = v > o ? o : v;
      v = (lower == desc) ? mx : mn;
    }
  }
  lds[tid] = v;
  __syncthreads();
}

__device__ inline unsigned long long pack_key(float f, int tid) {
  unsigned int u = __float_as_uint(f);
  u = (u & 0x80000000u) ? ~u : (u | 0x80000000u);   // order-preserving map
  return ((unsigned long long)u << 32) | (unsigned int)(NPERG - 1 - tid);
}

// layer-1: sort keys; 16 waves normalize+mean+sort the 32 selected h1 rows.
__global__ __launch_bounds__(1024) void topk_pool1(const float* __restrict__ keyb,
                                                   const float* __restrict__ h1,
                                                   const float* __restrict__ scale,
                                                   const float* __restrict__ shift,
                                                   float* __restrict__ r) {
  __shared__ unsigned long long lds[NPERG];
  const int b = blockIdx.x, tid = threadIdx.x;
  unsigned long long v = pack_key(keyb[b * NPERG + tid], tid);
  bitonic_sort1024(v, lds, tid);
  const int wave = tid >> 6, lane = tid & 63;
  #pragma unroll
  for (int q = 0; q < 2; ++q) {
    int rank = wave * 2 + q;
    int node = (int)(NPERG - 1 - (unsigned int)(lds[rank] & 0xFFFFFFFFu));
    size_t base = ((size_t)(b * NPERG + node)) * 256;
    float s = 0.f;
    #pragma unroll
    for (int h = 0; h < 4; ++h) {
      int ch = h * 64 + lane;
      float y = fmaf(scale[b * 256 + ch], h1[base + ch], shift[b * 256 + ch]);
      y = y >= 0.f ? y : 0.01f * y;
      s += y;
    }
    float val = bitonic_sort64(0.25f * s, lane);
    r[(size_t)b * 4096 + rank * 64 + lane] = val;
  }
}

// layer-2: same with h2 (C=128, H=2), writes at +2048.
__global__ __launch_bounds__(1024) void topk_pool2(const float* __restrict__ keyb,
                                                   const float* __restrict__ h2,
                                                   const float* __restrict__ scale,
                                                   const float* __restrict__ shift,
                                                   float* __restrict__ r) {
  __shared__ unsigned long long lds[NPERG];
  const int b = blockIdx.x, tid = threadIdx.x;
  unsigned long long v = pack_key(keyb[b * NPERG + tid], tid);
  bitonic_sort1024(v, lds, tid);
  const int wave = tid >> 6, lane = tid & 63;
  #pragma unroll
  for (int q = 0; q < 2; ++q) {
    int rank = wave * 2 + q;
    int node = (int)(NPERG - 1 - (unsigned int)(lds[rank] & 0xFFFFFFFFu));
    size_t base = ((size_t)(b * NPERG + node)) * 128;
    float s = 0.f;
    #pragma unroll
    for (int h = 0; h < 2; ++h) {
      int ch = h * 64 + lane;
      float y = fmaf(scale[b * 128 + ch], h2[base + ch], shift[b * 128 + ch]);
      y = y >= 0.f ? y : 0.01f * y;
      s += y;
    }
    float val = bitonic_sort64(0.5f * s, lane);
    r[(size_t)b * 4096 + 2048 + rank * 64 + lane] = val;
  }
}

// ---------------- FC head ----------------
__global__ __launch_bounds__(256) void fc1_partial(const float* __restrict__ r,
                                                   const float* __restrict__ w,
                                                   float* __restrict__ part) {
  __shared__ float rs_t[64][36];   // [k][m]
  const int ks = blockIdx.x, nb = blockIdx.y;
  const int tid = threadIdx.x;
  const int tx = tid & 63;
  const int ty = tid >> 6;

  #pragma unroll
  for (int t = 0; t < 8; ++t) {
    int elem = t * 256 + tid;
    int m = elem >> 6, k = elem & 63;
    rs_t[k][m] = r[(size_t)m * 4096 + ks * 64 + k];
  }
  __syncthreads();

  const float* wp = w + (size_t)(ks * 64) * 2048 + nb * 256 + tx * 4;
  float4 acc[8];
  #pragma unroll
  for (int i = 0; i < 8; ++i) acc[i] = make_float4(0.f, 0.f, 0.f, 0.f);

  #pragma unroll 4
  for (int k = 0; k < 64; ++k) {
    float4 wv = *(const float4*)&wp[(size_t)k * 2048];
    float4 ra = *(const float4*)&rs_t[k][ty * 8];
    float4 rb = *(const float4*)&rs_t[k][ty * 8 + 4];
    float rr[8] = {ra.x, ra.y, ra.z, ra.w, rb.x, rb.y, rb.z, rb.w};
    #pragma unroll
    for (int i = 0; i < 8; ++i) {
      acc[i].x = fmaf(rr[i], wv.x, acc[i].x);
      acc[i].y = fmaf(rr[i], wv.y, acc[i].y);
      acc[i].z = fmaf(rr[i], wv.z, acc[i].z);
      acc[i].w = fmaf(rr[i], wv.w, acc[i].w);
    }
  }

  #pragma unroll
  for (int i = 0; i < 8; ++i) {
    int m = ty * 8 + i;
    *(float4*)&part[((size_t)ks * 32 + m) * 2048 + nb * 256 + tx * 4] = acc[i];
  }
}

__global__ __launch_bounds__(256) void fc1_reduce(const float* __restrict__ part,
                                                  const float* __restrict__ bias,
                                                  float* __restrict__ hidden) {
  int idx = blockIdx.x * 256 + threadIdx.x;  // 32*512 (m, n4)
  int m = idx >> 9, n4 = idx & 511;
  const float* pp = part + (size_t)m * 2048 + n4 * 4;
  float4 b4 = *(const float4*)&bias[n4 * 4];
  float4 s = b4;
  #pragma unroll 8
  for (int ks = 0; ks < FC1_KS; ++ks) {
    float4 v = *(const float4*)&pp[(size_t)ks * 32 * 2048];
    s.x += v.x; s.y += v.y; s.z += v.z; s.w += v.w;
  }
  s.x = fmaxf(s.x, 0.f); s.y = fmaxf(s.y, 0.f);
  s.z = fmaxf(s.z, 0.f); s.w = fmaxf(s.w, 0.f);
  *(float4*)&hidden[(size_t)m * 2048 + n4 * 4] = s;
}

__global__ void fc2_kernel(const float* __restrict__ hidden, const float* __restrict__ w,
                           const float* __restrict__ bias, float* __restrict__ out) {
  int wid = (blockIdx.x * blockDim.x + threadIdx.x) >> 6;  // 512 waves
  int lane = threadIdx.x & 63;
  int m = wid >> 4, o = wid & 15;
  float s = 0.f;
  for (int k = lane; k < 2048; k += 64) s = fmaf(hidden[(size_t)m * 2048 + k], w[k * 16 + o], s);
  s = wave_reduce_sum(s);
  if (lane == 0) out[m * 16 + o] = s + bias[o];
}

// ---------------- launch ----------------
extern "C" void kernel_launch(void* const* d_in, const int* in_sizes, int n_in,
                              void* d_out, int out_size, void* d_ws, size_t ws_size,
                              hipStream_t stream) {
  const float* features = (const float*)d_in[0];
  const int* src = (const int*)d_in[1];
  const int* dst = (const int*)d_in[2];
  const float* W1 = (const float*)d_in[3];
  const float* al1 = (const float*)d_in[4];
  const float* ar1 = (const float*)d_in[5];
  const float* W2 = (const float*)d_in[6];
  const float* al2 = (const float*)d_in[7];
  const float* ar2 = (const float*)d_in[8];
  const float* gn1a = (const float*)d_in[9];
  const float* gn1g = (const float*)d_in[10];
  const float* gn1b = (const float*)d_in[11];
  const float* gn2a = (const float*)d_in[12];
  const float* gn2g = (const float*)d_in[13];
  const float* gn2b = (const float*)d_in[14];
  const float* fc1w = (const float*)d_in[15];
  const float* fc1b = (const float*)d_in[16];
  const float* fc2w = (const float*)d_in[17];
  const float* fc2b = (const float*)d_in[18];
  float* out = (float*)d_out;
  const int E_ = in_sizes[1];

  float* ws = (float*)d_ws;
  size_t off = 0;
  float* A = ws + off;      off += (size_t)NNODES * 256;  // f1 | (f2, h2) | fc1 part
  float* Bb = ws + off;     off += (size_t)NNODES * 256;  // h1 | hidden
  float* el1 = ws + off;    off += (size_t)NNODES * 4;
  float* er1 = ws + off;    off += (size_t)NNODES * 4;
  float* el2 = ws + off;    off += (size_t)NNODES * 2;
  float* er2 = ws + off;    off += (size_t)NNODES * 2;
  float* sc1 = ws + off;    off += 32 * 256;
  float* sh1 = ws + off;    off += 32 * 256;
  float* sc2 = ws + off;    off += 32 * 128;
  float* sh2 = ws + off;    off += 32 * 128;
  float* ps = ws + off;     off += 32 * 16 * 256;
  float* ps2 = ws + off;    off += 32 * 16 * 256;
  float* rbuf = ws + off;   off += 32 * 4096;
  float* keyb = ws + off;   off += NNODES;
  int* ibase = (int*)(ws + off);
  int* counts = ibase;
  int* rowptr = counts + NNODES;
  int* cursor = rowptr + NNODES + 1;
  int* csrsrc = cursor + NNODES;

  float* f1 = A;
  float* h1 = Bb;
  float* f2 = A;                                    // f1 dead after gat_agg<4>
  float* h2 = A + (size_t)NNODES * 128;
  float* part = A;                                  // f2 dead after gat_agg<2>
  float* hidden = Bb;                               // h1 dead after gemm2/topk_pool1

  hipMemsetAsync(counts, 0, NNODES * sizeof(int), stream);
  csr_count<<<(E_ + 255) / 256, 256, 0, stream>>>(dst, counts, E_);
  csr_scan<<<1, 1024, 0, stream>>>(counts, rowptr, cursor);
  csr_fill<<<(E_ + 255) / 256, 256, 0, stream>>>(src, dst, cursor, csrsrc, E_);

  dim3 g1(NNODES / 64, 4);
  gemm_fused<64, 256, 4><<<g1, 256, 0, stream>>>(features, W1, al1, ar1, f1, el1, er1);
  gat_agg<4><<<NNODES / 4, 256, 0, stream>>>(f1, el1, er1, rowptr, csrsrc, h1);

  gn_stats_partial<256><<<NGRAPH * 16, 256, 0, stream>>>(h1, ps, ps2);
  gn_stats_final<256><<<NGRAPH, 256, 0, stream>>>(ps, ps2, gn1a, gn1g, gn1b, sc1, sh1);
  gn_keys<256, 4><<<NNODES / 4, 256, 0, stream>>>(h1, sc1, sh1, keyb);

  topk_pool1<<<NGRAPH, 1024, 0, stream>>>(keyb, h1, sc1, sh1, rbuf);

  dim3 g2(NNODES / 64, 2);
  gemm2_fused<<<g2, 256, 0, stream>>>(h1, sc1, sh1, W2, al2, ar2, f2, el2, er2);
  gat_agg<2><<<NNODES / 4, 256, 0, stream>>>(f2, el2, er2, rowptr, csrsrc, h2);

  gn_stats_partial<128><<<NGRAPH * 16, 128, 0, stream>>>(h2, ps, ps2);
  gn_stats_final<128><<<NGRAPH, 128, 0, stream>>>(ps, ps2, gn2a, gn2g, gn2b, sc2, sh2);
  gn_keys<128, 2><<<NNODES / 4, 256, 0, stream>>>(h2, sc2, sh2, keyb);

  topk_pool2<<<NGRAPH, 1024, 0, stream>>>(keyb, h2, sc2, sh2, rbuf);

  dim3 gfc(FC1_KS, 8);
  fc1_partial<<<gfc, 256, 0, stream>>>(rbuf, fc1w, part);
  fc1_reduce<<<32 * 2048 / 1024, 256, 0, stream>>>(part, fc1b, hidden);
  fc2_kernel<<<128, 256, 0, stream>>>(hidden, fc2w, fc2b, out);
}